// Round 1
// baseline (314.381 us; speedup 1.0000x reference)
//
#include <hip/hip_runtime.h>

#define BINS 10

// One streaming pass: per-bin BCE sums + counts.
// loss = sum_b S_b / (c_b * n_nonempty)   (tot cancels algebraically)
__global__ __launch_bounds__(256) void ghm_partial(
    const float4* __restrict__ p4,
    const float4* __restrict__ t4,
    float* __restrict__ gsum,          // [BINS] in d_ws
    unsigned int* __restrict__ gcnt,   // [BINS] in d_ws
    int n4)
{
    __shared__ float ls[BINS];
    __shared__ float lc[BINS];
    const int tid = threadIdx.x;
    if (tid < BINS) { ls[tid] = 0.0f; lc[tid] = 0.0f; }
    __syncthreads();

    float sums[BINS];
    float cnts[BINS];
#pragma unroll
    for (int b = 0; b < BINS; ++b) { sums[b] = 0.0f; cnts[b] = 0.0f; }

    const int start  = blockIdx.x * blockDim.x + threadIdx.x;
    const int stride = gridDim.x * blockDim.x;

    for (int i = start; i < n4; i += stride) {
        float4 p = p4[i];
        float4 t = t4[i];
        float pe[4] = {p.x, p.y, p.z, p.w};
        float te[4] = {t.x, t.y, t.z, t.w};
#pragma unroll
        for (int e = 0; e < 4; ++e) {
            float pp = pe[e], tt = te[e];
            // targets are exactly 0.0f or 1.0f
            float g = fabsf(pp - tt);                 // same op as reference
            float q = (tt > 0.5f) ? pp : (1.0f - pp); // bce = -log(q)
            float bce = -__logf(q);
            int bi = (int)(g * 10.0f);                // floor (g >= 0)
            bi = bi > (BINS - 1) ? (BINS - 1) : bi;
#pragma unroll
            for (int b = 0; b < BINS; ++b) {
                bool m = (bi == b);
                sums[b] += m ? bce  : 0.0f;
                cnts[b] += m ? 1.0f : 0.0f;
            }
        }
    }

    // wave (64-lane) shuffle reduction, then LDS, then one global atomic per bin
    const int lane = threadIdx.x & 63;
#pragma unroll
    for (int b = 0; b < BINS; ++b) {
        float s = sums[b], c = cnts[b];
#pragma unroll
        for (int off = 32; off > 0; off >>= 1) {
            s += __shfl_down(s, off);
            c += __shfl_down(c, off);
        }
        if (lane == 0) {
            atomicAdd(&ls[b], s);
            atomicAdd(&lc[b], c);
        }
    }
    __syncthreads();
    if (tid < BINS) {
        atomicAdd(&gsum[tid], ls[tid]);
        // per-block count <= 256*~64 elems, exact in float; convert to int
        atomicAdd(&gcnt[tid], (unsigned int)lc[tid]);
    }
}

__global__ void ghm_finalize(const float* __restrict__ gsum,
                             const unsigned int* __restrict__ gcnt,
                             float* __restrict__ out)
{
    if (threadIdx.x == 0 && blockIdx.x == 0) {
        int n = 0;
#pragma unroll
        for (int b = 0; b < BINS; ++b) n += (gcnt[b] > 0) ? 1 : 0;
        float nn = (float)(n > 0 ? n : 1);
        float acc = 0.0f;
#pragma unroll
        for (int b = 0; b < BINS; ++b) {
            if (gcnt[b] > 0)
                acc += gsum[b] / ((float)gcnt[b] * nn);
        }
        out[0] = acc;
    }
}

extern "C" void kernel_launch(void* const* d_in, const int* in_sizes, int n_in,
                              void* d_out, int out_size, void* d_ws, size_t ws_size,
                              hipStream_t stream)
{
    const float* p = (const float*)d_in[0];   // inputs (probabilities)
    const float* t = (const float*)d_in[1];   // targets (0/1 floats)
    const int n  = in_sizes[0];               // 262144*128, divisible by 4
    const int n4 = n >> 2;

    float*        gsum = (float*)d_ws;
    unsigned int* gcnt = (unsigned int*)((char*)d_ws + BINS * sizeof(float));

    // d_ws is re-poisoned to 0xAA before every timed launch — zero it (capturable)
    hipMemsetAsync(d_ws, 0, BINS * (sizeof(float) + sizeof(unsigned int)), stream);

    const int threads = 256;
    const int blocks  = 2048;  // 8 blocks/CU, grid-stride covers any n4
    ghm_partial<<<blocks, threads, 0, stream>>>(
        (const float4*)p, (const float4*)t, gsum, gcnt, n4);

    ghm_finalize<<<1, 64, 0, stream>>>(gsum, gcnt, (float*)d_out);
}